// Round 25
// baseline (42.292 us; speedup 1.0000x reference)
//
#include <hip/hip_runtime.h>
#include <cstddef>

#define HDIM 2048
#define NE 64
#define TOPK 4

typedef short short8 __attribute__((ext_vector_type(8)));
typedef float f32x4 __attribute__((ext_vector_type(4)));

// fp16 round-to-nearest 2-way split with scaled residual plane:
// a = (float)h0 + (float)h1 * 2^-12, error ~ |a|*2^-24.
__device__ __forceinline__ void split2u(float a, unsigned short& h0, unsigned short& h1) {
    _Float16 x0 = (_Float16)a;
    float r = a - (float)x0;
    _Float16 x1 = (_Float16)(r * 4096.0f);
    h0 = __builtin_bit_cast(unsigned short, x0);
    h1 = __builtin_bit_cast(unsigned short, x1);
}

// MFMA wrapper: raw short8 bit-patterns, bitcast to f16 vectors at the call.
__device__ __forceinline__ f32x4 mfma_f16(short8 a, short8 b, f32x4 c) {
    typedef _Float16 f16x8_t __attribute__((ext_vector_type(8)));
    return __builtin_amdgcn_mfma_f32_16x16x32_f16(
        __builtin_bit_cast(f16x8_t, a), __builtin_bit_cast(f16x8_t, b), c, 0, 0, 0);
}

// ---------- prepass (r24-proven): B fragments, 2 fp16 planes as ushort ----------
// wtb[plane][s(64)][n(4)][lane(64)][j(8)]: e = 16n + (lane&15), k = 32s + 8*(lane>>4) + j
__global__ __launch_bounds__(256) void prep_b_kernel(
    const float* __restrict__ w, const float* __restrict__ scale,
    unsigned short* __restrict__ wtb)
{
    const int s = blockIdx.x;          // 0..63
    const int n = threadIdx.x >> 6;    // 0..3
    const int l = threadIdx.x & 63;
    const int e = 16 * n + (l & 15);
    const int k = 32 * s + 8 * (l >> 4);
    unsigned short h0[8], h1[8];
    #pragma unroll
    for (int j = 0; j < 8; ++j) {
        float v = w[(size_t)e * HDIM + k + j] * scale[k + j];
        split2u(v, h0[j], h1[j]);
    }
    size_t off = ((size_t)s * 4 + n) * 512 + (size_t)l * 8;
    #pragma unroll
    for (int j = 0; j < 8; ++j) {
        wtb[off + j]          = h0[j];
        wtb[131072 + off + j] = h1[j];
    }
}

// ---------- fused (r24-proven + A-prefetch depth 2) ----------
// fp16 split-2: 24 MFMA/wave/kstep -> matrix-pipe round ~930 cyc vs HBM ~900:
// depth-1 A prefetch was exactly marginal. Aq[3][4] gives ~1860 cyc cover.
__global__ __launch_bounds__(256) void fused_router_kernel(
    const float* __restrict__ x, const unsigned short* __restrict__ wtb,
    const float* __restrict__ pes,
    float* __restrict__ probs, float* __restrict__ tkw, float* __restrict__ tki)
{
    __shared__ float Sp[4][32 * 65];   // per-kh score partials
    __shared__ float Pl[32 * 65];
    __shared__ float SQp[4][32];
    __shared__ float FN[32];
    __shared__ float RS[32];

    const int tid = threadIdx.x;
    const int kh = tid >> 6;           // K-quarter 0..3
    const int l = tid & 63;
    const int tok0 = blockIdx.x * 32;
    const int m = l & 15;              // A row / B col within tile
    const int g = l >> 4;              // k-group

    const float* xr0 = x + (size_t)(tok0 + m) * HDIM + 512 * kh + 8 * g;   // tile 0
    const float* xr1 = xr0 + (size_t)16 * HDIM;                             // tile 1
    const unsigned short* wb = wtb + (size_t)(16 * kh) * 2048 + (size_t)l * 8;

    f32x4 accH0[4], accL0[4], accH1[4], accL1[4];
    #pragma unroll
    for (int n = 0; n < 4; ++n) {
        accH0[n] = (f32x4){0.f, 0.f, 0.f, 0.f};
        accL0[n] = (f32x4){0.f, 0.f, 0.f, 0.f};
        accH1[n] = (f32x4){0.f, 0.f, 0.f, 0.f};
        accL1[n] = (f32x4){0.f, 0.f, 0.f, 0.f};
    }
    float ssq0 = 0.f, ssq1 = 0.f;

    float4 Aq[3][4];                   // A triple-buffer: depth-2 prefetch
    short8 Bb[2][8];                   // B dbuf: [buf][2n + plane]

#define LOADA(buf, s) { \
        Aq[buf][0] = *(const float4*)(xr0 + 32 * (s)); \
        Aq[buf][1] = *(const float4*)(xr0 + 32 * (s) + 4); \
        Aq[buf][2] = *(const float4*)(xr1 + 32 * (s)); \
        Aq[buf][3] = *(const float4*)(xr1 + 32 * (s) + 4); }
#define LOADB(buf, s) { \
        const unsigned short* bs_ = wb + (size_t)(s) * 2048; \
        _Pragma("unroll") \
        for (int n = 0; n < 4; ++n) { \
            Bb[buf][2*n + 0] = *(const short8*)(bs_ + n * 512); \
            Bb[buf][2*n + 1] = *(const short8*)(bs_ + n * 512 + 131072); } }

    LOADA(0, 0);
    LOADA(1, 1);
    LOADB(0, 0);

    #pragma unroll
    for (int s = 0; s < 16; ++s) {
        const int acur = s % 3;                        // static under full unroll
        const int bcur = s & 1;
        if (s + 2 < 16) LOADA((s + 2) % 3, s + 2);     // A: 2 ksteps ahead (~1860 cyc cover)
        if (s + 1 < 16) LOADB(bcur ^ 1, s + 1);        // B: 1 kstep ahead (L2-hot)

        float af0[8], af1[8];
        *(float4*)af0 = Aq[acur][0]; *(float4*)(af0 + 4) = Aq[acur][1];
        *(float4*)af1 = Aq[acur][2]; *(float4*)(af1 + 4) = Aq[acur][3];
        unsigned short p0[8], p1[8], q0[8], q1[8];
        #pragma unroll
        for (int j = 0; j < 8; ++j) {
            split2u(af0[j], p0[j], p1[j]);
            split2u(af1[j], q0[j], q1[j]);
            ssq0 = fmaf(af0[j], af0[j], ssq0);
            ssq1 = fmaf(af1[j], af1[j], ssq1);
        }
        short8 a0, a1, c0, c1;
        #pragma unroll
        for (int j = 0; j < 8; ++j) {
            a0[j] = (short)p0[j]; a1[j] = (short)p1[j];
            c0[j] = (short)q0[j]; c1[j] = (short)q1[j];
        }
        __builtin_amdgcn_s_setprio(1);
        #pragma unroll
        for (int n = 0; n < 4; ++n) {
            short8 b0 = Bb[bcur][2*n + 0];
            short8 b1 = Bb[bcur][2*n + 1];
            accH0[n] = mfma_f16(a0, b0, accH0[n]);
            accL0[n] = mfma_f16(a0, b1, accL0[n]);
            accL0[n] = mfma_f16(a1, b0, accL0[n]);
            accH1[n] = mfma_f16(c0, b0, accH1[n]);
            accL1[n] = mfma_f16(c0, b1, accL1[n]);
            accL1[n] = mfma_f16(c1, b0, accL1[n]);
        }
        __builtin_amdgcn_s_setprio(0);
    }
#undef LOADA
#undef LOADB

    // ssq: sum the 4 k-group lanes per token (lanes differ in bits 4,5)
    ssq0 += __shfl_xor(ssq0, 16, 64);
    ssq0 += __shfl_xor(ssq0, 32, 64);
    ssq1 += __shfl_xor(ssq1, 16, 64);
    ssq1 += __shfl_xor(ssq1, 32, 64);

    // ---- stage merged partials (s = accH + accL*2^-12) ----
    const float LSC = 1.0f / 4096.0f;
    #pragma unroll
    for (int n = 0; n < 4; ++n)
        #pragma unroll
        for (int r = 0; r < 4; ++r) {   // D: col=lane&15, row=4*(lane>>4)+reg [m89]
            Sp[kh][(4 * g + r) * 65 + 16 * n + m]      = fmaf(accL0[n][r], LSC, accH0[n][r]);
            Sp[kh][(16 + 4 * g + r) * 65 + 16 * n + m] = fmaf(accL1[n][r], LSC, accH1[n][r]);
        }
    if (l < 16) {
        SQp[kh][m]      = ssq0;
        SQp[kh][16 + m] = ssq1;
    }
    __syncthreads();

    if (tid < 32) {
        float q0 = (SQp[0][tid] + SQp[1][tid]) + (SQp[2][tid] + SQp[3][tid]);
        FN[tid] = rsqrtf(q0 * (1.0f / HDIM) + 1e-6f) * 0.022097086912079612f;
    }
    __syncthreads();

    #pragma unroll
    for (int qq = 0; qq < 2; qq++) {    // combine 4 partials: 512 float4 over 2 passes
        int f = tid + 256 * qq;
        int mr = f >> 4;
        int e4 = (f & 15) * 4;
        int base = mr * 65 + e4;
        float4 t0 = *(const float4*)&Sp[0][base];
        float4 t1 = *(const float4*)&Sp[1][base];
        float4 t2 = *(const float4*)&Sp[2][base];
        float4 t3 = *(const float4*)&Sp[3][base];
        float fn = FN[mr];
        float4 sv;
        sv.x = ((t0.x + t1.x) + (t2.x + t3.x)) * fn;
        sv.y = ((t0.y + t1.y) + (t2.y + t3.y)) * fn;
        sv.z = ((t0.z + t1.z) + (t2.z + t3.z)) * fn;
        sv.w = ((t0.w + t1.w) + (t2.w + t3.w)) * fn;
        *(float4*)&Sp[0][base] = sv;    // Sl == Sp[0]
    }
    __syncthreads();

    float* Sl = &Sp[0][0];

    // ---- proven epilogue (32 tokens) ----
    if (tid < 32) {
        const int mm = tid;
        float mx = -3.0e38f;
        for (int e = 0; e < NE; e++) mx = fmaxf(mx, Sl[mm * 65 + e]);
        float sum = 0.f;
        for (int e = 0; e < NE; e++) {
            float p = __expf(Sl[mm * 65 + e] - mx);
            Pl[mm * 65 + e] = p;
            sum += p;
        }
        RS[mm] = 1.0f / sum;
    }
    __syncthreads();

    #pragma unroll
    for (int qq = 0; qq < 2; qq++) {    // coalesced probs write: 512 float4 over 2 passes
        int f = tid + 256 * qq;
        int mr = f >> 4;
        int e0 = (f & 15) * 4;
        float rs = RS[mr];
        float4 pv;
        pv.x = Pl[mr * 65 + e0 + 0] * rs;
        pv.y = Pl[mr * 65 + e0 + 1] * rs;
        pv.z = Pl[mr * 65 + e0 + 2] * rs;
        pv.w = Pl[mr * 65 + e0 + 3] * rs;
        *(float4*)&probs[(size_t)(tok0 + mr) * NE + e0] = pv;
    }

    if (tid < 32) {                      // destructive top-4, lowest-index ties
        const int mm = tid;
        float wvv[TOPK]; int idx[TOPK];
        float wsum = 0.f;
        #pragma unroll
        for (int kk = 0; kk < TOPK; ++kk) {
            float best = -3.0e38f; int bi = 0;
            for (int e = 0; e < NE; e++) {
                float v = Sl[mm * 65 + e];
                if (v > best) { best = v; bi = e; }
            }
            Sl[mm * 65 + bi] = -3.4e38f;
            float p = Pl[mm * 65 + bi];
            wvv[kk] = p; idx[kk] = bi; wsum += p;
        }
        float inv = 1.0f / wsum;
        size_t ob = (size_t)(tok0 + mm) * TOPK;
        #pragma unroll
        for (int kk = 0; kk < TOPK; kk++) {
            tkw[ob + kk] = wvv[kk] * inv * pes[idx[kk]];
            tki[ob + kk] = (float)idx[kk];   // harness reads flat buffer as float32
        }
    }
}

extern "C" void kernel_launch(void* const* d_in, const int* in_sizes, int n_in,
                              void* d_out, int out_size, void* d_ws, size_t ws_size,
                              hipStream_t stream) {
    const float* x     = (const float*)d_in[0];
    const float* w     = (const float*)d_in[1];
    const float* scale = (const float*)d_in[2];
    const float* pes   = (const float*)d_in[3];
    const int tokens = in_sizes[0] / HDIM;      // 16384

    float* probs = (float*)d_out;
    float* tkw   = probs + (size_t)tokens * NE;
    float* tki   = tkw + (size_t)tokens * TOPK;

    unsigned short* wtb = (unsigned short*)d_ws;   // 2 planes x 256 KB = 512 KB

    prep_b_kernel<<<HDIM / 32, 256, 0, stream>>>(w, scale, wtb);

    const int grid = tokens / 32;               // 512 -> 2 blocks/CU
    fused_router_kernel<<<grid, 256, 0, stream>>>(x, wtb, pes, probs, tkw, tki);
}

// Round 26
// 41.347 us; speedup vs baseline: 1.0229x; 1.0229x over previous
//
#include <hip/hip_runtime.h>
#include <cstddef>

#define HDIM 2048
#define NE 64
#define TOPK 4

typedef short short8 __attribute__((ext_vector_type(8)));
typedef float f32x4 __attribute__((ext_vector_type(4)));

// fp16 round-to-nearest 2-way split with scaled residual plane:
// a = (float)h0 + (float)h1 * 2^-12, error ~ |a|*2^-24.
__device__ __forceinline__ void split2u(float a, unsigned short& h0, unsigned short& h1) {
    _Float16 x0 = (_Float16)a;
    float r = a - (float)x0;
    _Float16 x1 = (_Float16)(r * 4096.0f);
    h0 = __builtin_bit_cast(unsigned short, x0);
    h1 = __builtin_bit_cast(unsigned short, x1);
}

// MFMA wrapper: raw short8 bit-patterns, bitcast to f16 vectors at the call.
__device__ __forceinline__ f32x4 mfma_f16(short8 a, short8 b, f32x4 c) {
    typedef _Float16 f16x8_t __attribute__((ext_vector_type(8)));
    return __builtin_amdgcn_mfma_f32_16x16x32_f16(
        __builtin_bit_cast(f16x8_t, a), __builtin_bit_cast(f16x8_t, b), c, 0, 0, 0);
}

// ---------- prepass: B fragments, 2 fp16 planes (b0, b1*2^12) as ushort ----------
// wtb[plane][s(64)][n(4)][lane(64)][j(8)]: e = 16n + (lane&15), k = 32s + 8*(lane>>4) + j
__global__ __launch_bounds__(256) void prep_b_kernel(
    const float* __restrict__ w, const float* __restrict__ scale,
    unsigned short* __restrict__ wtb)
{
    const int s = blockIdx.x;          // 0..63
    const int n = threadIdx.x >> 6;    // 0..3
    const int l = threadIdx.x & 63;
    const int e = 16 * n + (l & 15);
    const int k = 32 * s + 8 * (l >> 4);
    unsigned short h0[8], h1[8];
    #pragma unroll
    for (int j = 0; j < 8; ++j) {
        float v = w[(size_t)e * HDIM + k + j] * scale[k + j];
        split2u(v, h0[j], h1[j]);
    }
    size_t off = ((size_t)s * 4 + n) * 512 + (size_t)l * 8;
    #pragma unroll
    for (int j = 0; j < 8; ++j) {
        wtb[off + j]          = h0[j];
        wtb[131072 + off + j] = h1[j];
    }
}

// ---------- fused: fp16 split-2 (3 MFMA per tile-n), r17-proven skeleton ----------
// Block = 32 tokens, 4 waves = K-quarters (kh=0..3, 16 ksteps each), grid 512.
// Per wave: 32 tok x 64 exp x 512 K. accH (scale 1) + accL (scale 2^-12).
// Best-known configuration (r24: 41.34 us, absmax 0.001953125).
__global__ __launch_bounds__(256) void fused_router_kernel(
    const float* __restrict__ x, const unsigned short* __restrict__ wtb,
    const float* __restrict__ pes,
    float* __restrict__ probs, float* __restrict__ tkw, float* __restrict__ tki)
{
    __shared__ float Sp[4][32 * 65];   // per-kh score partials
    __shared__ float Pl[32 * 65];
    __shared__ float SQp[4][32];
    __shared__ float FN[32];
    __shared__ float RS[32];

    const int tid = threadIdx.x;
    const int kh = tid >> 6;           // K-quarter 0..3
    const int l = tid & 63;
    const int tok0 = blockIdx.x * 32;
    const int m = l & 15;              // A row / B col within tile
    const int g = l >> 4;              // k-group

    const float* xr0 = x + (size_t)(tok0 + m) * HDIM + 512 * kh + 8 * g;   // tile 0
    const float* xr1 = xr0 + (size_t)16 * HDIM;                             // tile 1
    const unsigned short* wb = wtb + (size_t)(16 * kh) * 2048 + (size_t)l * 8;

    f32x4 accH0[4], accL0[4], accH1[4], accL1[4];
    #pragma unroll
    for (int n = 0; n < 4; ++n) {
        accH0[n] = (f32x4){0.f, 0.f, 0.f, 0.f};
        accL0[n] = (f32x4){0.f, 0.f, 0.f, 0.f};
        accH1[n] = (f32x4){0.f, 0.f, 0.f, 0.f};
        accL1[n] = (f32x4){0.f, 0.f, 0.f, 0.f};
    }
    float ssq0 = 0.f, ssq1 = 0.f;

    float4 Aq[2][4];                   // A dbuf: [buf][tile*2 + half]
    short8 Bb[2][8];                   // B dbuf: [buf][2n + plane]

#define LOADA(buf, s) { \
        Aq[buf][0] = *(const float4*)(xr0 + 32 * (s)); \
        Aq[buf][1] = *(const float4*)(xr0 + 32 * (s) + 4); \
        Aq[buf][2] = *(const float4*)(xr1 + 32 * (s)); \
        Aq[buf][3] = *(const float4*)(xr1 + 32 * (s) + 4); }
#define LOADB(buf, s) { \
        const unsigned short* bs_ = wb + (size_t)(s) * 2048; \
        _Pragma("unroll") \
        for (int n = 0; n < 4; ++n) { \
            Bb[buf][2*n + 0] = *(const short8*)(bs_ + n * 512); \
            Bb[buf][2*n + 1] = *(const short8*)(bs_ + n * 512 + 131072); } }

    LOADA(0, 0);
    LOADB(0, 0);

    #pragma unroll
    for (int s = 0; s < 16; ++s) {
        const int cur = s & 1, nxt = cur ^ 1;
        if (s + 1 < 16) { LOADA(nxt, s + 1); LOADB(nxt, s + 1); }  // next kstep in flight

        float af0[8], af1[8];
        *(float4*)af0 = Aq[cur][0]; *(float4*)(af0 + 4) = Aq[cur][1];
        *(float4*)af1 = Aq[cur][2]; *(float4*)(af1 + 4) = Aq[cur][3];
        unsigned short p0[8], p1[8], q0[8], q1[8];
        #pragma unroll
        for (int j = 0; j < 8; ++j) {
            split2u(af0[j], p0[j], p1[j]);
            split2u(af1[j], q0[j], q1[j]);
            ssq0 = fmaf(af0[j], af0[j], ssq0);
            ssq1 = fmaf(af1[j], af1[j], ssq1);
        }
        short8 a0, a1, c0, c1;
        #pragma unroll
        for (int j = 0; j < 8; ++j) {
            a0[j] = (short)p0[j]; a1[j] = (short)p1[j];
            c0[j] = (short)q0[j]; c1[j] = (short)q1[j];
        }
        __builtin_amdgcn_s_setprio(1);
        #pragma unroll
        for (int n = 0; n < 4; ++n) {
            short8 b0 = Bb[cur][2*n + 0];
            short8 b1 = Bb[cur][2*n + 1];
            accH0[n] = mfma_f16(a0, b0, accH0[n]);
            accL0[n] = mfma_f16(a0, b1, accL0[n]);
            accL0[n] = mfma_f16(a1, b0, accL0[n]);
            accH1[n] = mfma_f16(c0, b0, accH1[n]);
            accL1[n] = mfma_f16(c0, b1, accL1[n]);
            accL1[n] = mfma_f16(c1, b0, accL1[n]);
        }
        __builtin_amdgcn_s_setprio(0);
    }
#undef LOADA
#undef LOADB

    // ssq: sum the 4 k-group lanes per token (lanes differ in bits 4,5)
    ssq0 += __shfl_xor(ssq0, 16, 64);
    ssq0 += __shfl_xor(ssq0, 32, 64);
    ssq1 += __shfl_xor(ssq1, 16, 64);
    ssq1 += __shfl_xor(ssq1, 32, 64);

    // ---- stage merged partials (s = accH + accL*2^-12) ----
    const float LSC = 1.0f / 4096.0f;
    #pragma unroll
    for (int n = 0; n < 4; ++n)
        #pragma unroll
        for (int r = 0; r < 4; ++r) {   // D: col=lane&15, row=4*(lane>>4)+reg [m89]
            Sp[kh][(4 * g + r) * 65 + 16 * n + m]      = fmaf(accL0[n][r], LSC, accH0[n][r]);
            Sp[kh][(16 + 4 * g + r) * 65 + 16 * n + m] = fmaf(accL1[n][r], LSC, accH1[n][r]);
        }
    if (l < 16) {
        SQp[kh][m]      = ssq0;
        SQp[kh][16 + m] = ssq1;
    }
    __syncthreads();

    if (tid < 32) {
        float q0 = (SQp[0][tid] + SQp[1][tid]) + (SQp[2][tid] + SQp[3][tid]);
        FN[tid] = rsqrtf(q0 * (1.0f / HDIM) + 1e-6f) * 0.022097086912079612f;
    }
    __syncthreads();

    #pragma unroll
    for (int qq = 0; qq < 2; qq++) {    // combine 4 partials: 512 float4 over 2 passes
        int f = tid + 256 * qq;
        int mr = f >> 4;
        int e4 = (f & 15) * 4;
        int base = mr * 65 + e4;
        float4 t0 = *(const float4*)&Sp[0][base];
        float4 t1 = *(const float4*)&Sp[1][base];
        float4 t2 = *(const float4*)&Sp[2][base];
        float4 t3 = *(const float4*)&Sp[3][base];
        float fn = FN[mr];
        float4 sv;
        sv.x = ((t0.x + t1.x) + (t2.x + t3.x)) * fn;
        sv.y = ((t0.y + t1.y) + (t2.y + t3.y)) * fn;
        sv.z = ((t0.z + t1.z) + (t2.z + t3.z)) * fn;
        sv.w = ((t0.w + t1.w) + (t2.w + t3.w)) * fn;
        *(float4*)&Sp[0][base] = sv;    // Sl == Sp[0]
    }
    __syncthreads();

    float* Sl = &Sp[0][0];

    // ---- proven epilogue (32 tokens) ----
    if (tid < 32) {
        const int mm = tid;
        float mx = -3.0e38f;
        for (int e = 0; e < NE; e++) mx = fmaxf(mx, Sl[mm * 65 + e]);
        float sum = 0.f;
        for (int e = 0; e < NE; e++) {
            float p = __expf(Sl[mm * 65 + e] - mx);
            Pl[mm * 65 + e] = p;
            sum += p;
        }
        RS[mm] = 1.0f / sum;
    }
    __syncthreads();

    #pragma unroll
    for (int qq = 0; qq < 2; qq++) {    // coalesced probs write: 512 float4 over 2 passes
        int f = tid + 256 * qq;
        int mr = f >> 4;
        int e0 = (f & 15) * 4;
        float rs = RS[mr];
        float4 pv;
        pv.x = Pl[mr * 65 + e0 + 0] * rs;
        pv.y = Pl[mr * 65 + e0 + 1] * rs;
        pv.z = Pl[mr * 65 + e0 + 2] * rs;
        pv.w = Pl[mr * 65 + e0 + 3] * rs;
        *(float4*)&probs[(size_t)(tok0 + mr) * NE + e0] = pv;
    }

    if (tid < 32) {                      // destructive top-4, lowest-index ties
        const int mm = tid;
        float wvv[TOPK]; int idx[TOPK];
        float wsum = 0.f;
        #pragma unroll
        for (int kk = 0; kk < TOPK; ++kk) {
            float best = -3.0e38f; int bi = 0;
            for (int e = 0; e < NE; e++) {
                float v = Sl[mm * 65 + e];
                if (v > best) { best = v; bi = e; }
            }
            Sl[mm * 65 + bi] = -3.4e38f;
            float p = Pl[mm * 65 + bi];
            wvv[kk] = p; idx[kk] = bi; wsum += p;
        }
        float inv = 1.0f / wsum;
        size_t ob = (size_t)(tok0 + mm) * TOPK;
        #pragma unroll
        for (int kk = 0; kk < TOPK; kk++) {
            tkw[ob + kk] = wvv[kk] * inv * pes[idx[kk]];
            tki[ob + kk] = (float)idx[kk];   // harness reads flat buffer as float32
        }
    }
}

extern "C" void kernel_launch(void* const* d_in, const int* in_sizes, int n_in,
                              void* d_out, int out_size, void* d_ws, size_t ws_size,
                              hipStream_t stream) {
    const float* x     = (const float*)d_in[0];
    const float* w     = (const float*)d_in[1];
    const float* scale = (const float*)d_in[2];
    const float* pes   = (const float*)d_in[3];
    const int tokens = in_sizes[0] / HDIM;      // 16384

    float* probs = (float*)d_out;
    float* tkw   = probs + (size_t)tokens * NE;
    float* tki   = tkw + (size_t)tokens * TOPK;

    unsigned short* wtb = (unsigned short*)d_ws;   // 2 planes x 256 KB = 512 KB

    prep_b_kernel<<<HDIM / 32, 256, 0, stream>>>(w, scale, wtb);

    const int grid = tokens / 32;               // 512 -> 2 blocks/CU
    fused_router_kernel<<<grid, 256, 0, stream>>>(x, wtb, pes, probs, tkw, tki);
}